// Round 5
// baseline (1591.251 us; speedup 1.0000x reference)
//
#include <hip/hip_runtime.h>
#include <math.h>

// Problem constants
#define S_LEN 2048
#define HDIM  2048
#define NHEADS 16
#define NKVH   8
#define HD     128
#define FFDIM  6144
#define EPSV   1e-6f

// ---------------------------------------------------------------------------
// bf16 split helpers
// ---------------------------------------------------------------------------
__device__ __forceinline__ ushort f2bf(float f) {   // RNE
    unsigned u = __float_as_uint(f);
    u += 0x7FFF + ((u >> 16) & 1);
    return (ushort)(u >> 16);
}
__device__ __forceinline__ float bf2f(ushort h) {
    return __uint_as_float(((unsigned)h) << 16);
}

typedef __attribute__((ext_vector_type(8))) short bf16x8;
typedef __attribute__((ext_vector_type(4))) float f32x4;

__device__ __forceinline__ void glds16(const void* g, void* l) {
    __builtin_amdgcn_global_load_lds(
        (const __attribute__((address_space(1))) void*)g,
        (__attribute__((address_space(3))) void*)l, 16, 0, 0);
}

// ---------------------------------------------------------------------------
// RMSNorm over rows of 2048 -> bf16 hi/lo split output
// ---------------------------------------------------------------------------
__global__ __launch_bounds__(256) void rmsnorm_split_k(const float* __restrict__ in,
                                                       const float* __restrict__ w,
                                                       ushort* __restrict__ oh,
                                                       ushort* __restrict__ ol) {
    int s = blockIdx.x;
    int tid = threadIdx.x;
    const float* row = in + (size_t)s * HDIM;
    float ss = 0.0f;
    for (int i = tid; i < HDIM; i += 256) {
        float v = row[i];
        ss += v * v;
    }
    __shared__ float red[256];
    red[tid] = ss;
    __syncthreads();
    for (int off = 128; off > 0; off >>= 1) {
        if (tid < off) red[tid] += red[tid + off];
        __syncthreads();
    }
    float r = rsqrtf(red[0] / (float)HDIM + EPSV);
    for (int i = tid; i < HDIM; i += 256) {
        float v = row[i] * r * w[i];
        ushort h = f2bf(v);
        oh[(size_t)s * HDIM + i] = h;
        ol[(size_t)s * HDIM + i] = f2bf(v - bf2f(h));
    }
}

// ---------------------------------------------------------------------------
// Merged qkv weight transpose+split: z=0 -> q_w (32 xblk), z=1 -> k_w, z=2 -> v_w.
// Output rows: q at 0, k at 2048, v at 3072. grid (32, 32, 3).
// ---------------------------------------------------------------------------
__global__ __launch_bounds__(256) void transpose_split_qkv_k(
    const float* __restrict__ q_w, const float* __restrict__ k_w,
    const float* __restrict__ v_w, ushort* __restrict__ Th,
    ushort* __restrict__ Tl) {
    int z = blockIdx.z;
    int bx = blockIdx.x;
    if (z > 0 && bx >= 16) return;
    const float* W = (z == 0) ? q_w : ((z == 1) ? k_w : v_w);
    int Ntot = (z == 0) ? 2048 : 1024;
    int nout0 = (z == 0) ? 0 : ((z == 1) ? 2048 : 3072);
    __shared__ float t[64][65];
    int tid = threadIdx.x;
    int nt = bx * 64;
    int kt = blockIdx.y * 64;
#pragma unroll
    for (int p = 0; p < 4; ++p) {
        int idx = tid + p * 256;
        int kk = idx >> 4;
        int nn = (idx & 15) * 4;
        float4 v = *(const float4*)&W[(size_t)(kt + kk) * Ntot + nt + nn];
        t[nn + 0][kk] = v.x;
        t[nn + 1][kk] = v.y;
        t[nn + 2][kk] = v.z;
        t[nn + 3][kk] = v.w;
    }
    __syncthreads();
#pragma unroll
    for (int p = 0; p < 4; ++p) {
        int idx = tid + p * 256;
        int nn = idx >> 4;
        int kk = (idx & 15) * 4;
        ushort4 hv, lv;
        float a0 = t[nn][kk + 0], a1 = t[nn][kk + 1], a2 = t[nn][kk + 2], a3 = t[nn][kk + 3];
        hv.x = f2bf(a0); lv.x = f2bf(a0 - bf2f(hv.x));
        hv.y = f2bf(a1); lv.y = f2bf(a1 - bf2f(hv.y));
        hv.z = f2bf(a2); lv.z = f2bf(a2 - bf2f(hv.z));
        hv.w = f2bf(a3); lv.w = f2bf(a3 - bf2f(hv.w));
        size_t o = (size_t)(nout0 + nt + nn) * HDIM + kt + kk;
        *(ushort4*)&Th[o] = hv;
        *(ushort4*)&Tl[o] = lv;
    }
}

// ---------------------------------------------------------------------------
// Generic transpose + split: W[K][Ntot] (cols n0..) -> rows nout0.., [.][K] bf16
// ---------------------------------------------------------------------------
__global__ __launch_bounds__(256) void transpose_split_k(const float* __restrict__ W,
                                                         ushort* __restrict__ Th,
                                                         ushort* __restrict__ Tl,
                                                         int K, int Ntot, int n0,
                                                         int nout0) {
    __shared__ float t[64][65];
    int tid = threadIdx.x;
    int nt = blockIdx.x * 64;
    int kt = blockIdx.y * 64;
#pragma unroll
    for (int p = 0; p < 4; ++p) {
        int idx = tid + p * 256;
        int kk = idx >> 4;
        int nn = (idx & 15) * 4;
        float4 v = *(const float4*)&W[(size_t)(kt + kk) * Ntot + n0 + nt + nn];
        t[nn + 0][kk] = v.x;
        t[nn + 1][kk] = v.y;
        t[nn + 2][kk] = v.z;
        t[nn + 3][kk] = v.w;
    }
    __syncthreads();
#pragma unroll
    for (int p = 0; p < 4; ++p) {
        int idx = tid + p * 256;
        int nn = idx >> 4;
        int kk = (idx & 15) * 4;
        ushort4 hv, lv;
        float a0 = t[nn][kk + 0], a1 = t[nn][kk + 1], a2 = t[nn][kk + 2], a3 = t[nn][kk + 3];
        hv.x = f2bf(a0); lv.x = f2bf(a0 - bf2f(hv.x));
        hv.y = f2bf(a1); lv.y = f2bf(a1 - bf2f(hv.y));
        hv.z = f2bf(a2); lv.z = f2bf(a2 - bf2f(hv.z));
        hv.w = f2bf(a3); lv.w = f2bf(a3 - bf2f(hv.w));
        size_t o = (size_t)(nout0 + nt + nn) * K + kt + kk;
        *(ushort4*)&Th[o] = hv;
        *(ushort4*)&Tl[o] = lv;
    }
}

// ---------------------------------------------------------------------------
// gate/up interleaved transpose: out rows 128*bx + 64*z (z=0 gate, z=1 up),
// source cols n0 + bx*64 .. +64 of gate_w/up_w [HDIM][FFDIM]. grid (32,32,2).
// ---------------------------------------------------------------------------
__global__ __launch_bounds__(256) void transpose_split_gu_k(
    const float* __restrict__ gate_w, const float* __restrict__ up_w,
    ushort* __restrict__ Th, ushort* __restrict__ Tl, int n0) {
    int z = blockIdx.z;
    const float* W = z ? up_w : gate_w;
    __shared__ float t[64][65];
    int tid = threadIdx.x;
    int bx = blockIdx.x;
    int kt = blockIdx.y * 64;
    int nout0 = 128 * bx + 64 * z;
#pragma unroll
    for (int p = 0; p < 4; ++p) {
        int idx = tid + p * 256;
        int kk = idx >> 4;
        int nn = (idx & 15) * 4;
        float4 v = *(const float4*)&W[(size_t)(kt + kk) * FFDIM + n0 + bx * 64 + nn];
        t[nn + 0][kk] = v.x;
        t[nn + 1][kk] = v.y;
        t[nn + 2][kk] = v.z;
        t[nn + 3][kk] = v.w;
    }
    __syncthreads();
#pragma unroll
    for (int p = 0; p < 4; ++p) {
        int idx = tid + p * 256;
        int nn = idx >> 4;
        int kk = (idx & 15) * 4;
        ushort4 hv, lv;
        float a0 = t[nn][kk + 0], a1 = t[nn][kk + 1], a2 = t[nn][kk + 2], a3 = t[nn][kk + 3];
        hv.x = f2bf(a0); lv.x = f2bf(a0 - bf2f(hv.x));
        hv.y = f2bf(a1); lv.y = f2bf(a1 - bf2f(hv.y));
        hv.z = f2bf(a2); lv.z = f2bf(a2 - bf2f(hv.z));
        hv.w = f2bf(a3); lv.w = f2bf(a3 - bf2f(hv.w));
        size_t o = (size_t)(nout0 + nn) * HDIM + kt + kk;
        *(ushort4*)&Th[o] = hv;
        *(ushort4*)&Tl[o] = lv;
    }
}

// ---------------------------------------------------------------------------
// V conversion + transpose: strided fp32 (qkv cols 3072..4095) -> bf16 hi/lo
// [NKVH][HD][S], s-index XOR-swizzled within 64-blocks (s ^= (d&7)<<3).
// grid (S/64, HD/64, NKVH).
// ---------------------------------------------------------------------------
__global__ __launch_bounds__(256) void conv_vt_k(const float* __restrict__ vsrc,
                                                 ushort* __restrict__ oh,
                                                 ushort* __restrict__ ol) {
    __shared__ float t[64][65];
    int s0 = blockIdx.x * 64, d0 = blockIdx.y * 64, kvh = blockIdx.z;
    int tid = threadIdx.x;
#pragma unroll
    for (int p = 0; p < 4; ++p) {
        int c = tid + p * 256;
        int ss = c >> 4, d4 = (c & 15) * 4;
        float4 x = *(const float4*)&vsrc[(size_t)(s0 + ss) * 4096 + 3072 + kvh * 128 + d0 + d4];
        t[d4 + 0][ss] = x.x;
        t[d4 + 1][ss] = x.y;
        t[d4 + 2][ss] = x.z;
        t[d4 + 3][ss] = x.w;
    }
    __syncthreads();
#pragma unroll
    for (int p = 0; p < 4; ++p) {
        int c = tid + p * 256;
        int dd = c >> 4, s4 = (c & 15) * 4;
        int d = d0 + dd;
        int sx = s4 ^ ((d & 7) << 3);
        size_t obase = ((size_t)kvh * HD + d) * S_LEN + s0 + sx;
        ushort4 hv, lv;
        float a0 = t[dd][s4 + 0], a1 = t[dd][s4 + 1], a2 = t[dd][s4 + 2], a3 = t[dd][s4 + 3];
        unsigned u0 = __float_as_uint(a0), u1 = __float_as_uint(a1);
        unsigned u2 = __float_as_uint(a2), u3 = __float_as_uint(a3);
        hv.x = (ushort)(u0 >> 16); lv.x = (ushort)(__float_as_uint(a0 - __uint_as_float(u0 & 0xFFFF0000u)) >> 16);
        hv.y = (ushort)(u1 >> 16); lv.y = (ushort)(__float_as_uint(a1 - __uint_as_float(u1 & 0xFFFF0000u)) >> 16);
        hv.z = (ushort)(u2 >> 16); lv.z = (ushort)(__float_as_uint(a2 - __uint_as_float(u2 & 0xFFFF0000u)) >> 16);
        hv.w = (ushort)(u3 >> 16); lv.w = (ushort)(__float_as_uint(a3 - __uint_as_float(u3 & 0xFFFF0000u)) >> 16);
        *(ushort4*)&oh[obase] = hv;
        *(ushort4*)&ol[obase] = lv;
    }
}

// ---------------------------------------------------------------------------
// Per-head RMSNorm + RoPE reading strided qkv fp32, writing bf16 hi/lo split
// directly (q: linear layout; k: d-index XOR swizzled d^=(s&7)<<3).
// ---------------------------------------------------------------------------
__global__ __launch_bounds__(128) void qk_rope_split_k(
    const float* __restrict__ qkv, const float* __restrict__ nw,
    const int* __restrict__ positions, ushort* __restrict__ oh,
    ushort* __restrict__ ol, int nheads, int coloff, int swz) {
    int s = blockIdx.x;
    int h = blockIdx.y;
    int d = threadIdx.x;
    const float* row = qkv + (size_t)s * 4096 + coloff + h * HD;
    __shared__ float buf[HD];
    __shared__ float red[HD];
    float v = row[d];
    red[d] = v * v;
    __syncthreads();
    for (int off = 64; off > 0; off >>= 1) {
        if (d < off) red[d] += red[d + off];
        __syncthreads();
    }
    float r = rsqrtf(red[0] / (float)HD + EPSV);
    float nv = v * r * nw[d];
    buf[d] = nv;
    __syncthreads();
    float pos = (float)positions[s];
    int d2 = d & 63;
    float inv_freq = expf(-((float)(2 * d2) / 128.0f) * 13.815510557964274f);
    float freq = pos * inv_freq;
    float c, sn;
    sincosf(freq, &sn, &c);
    float rot = (d < 64) ? -buf[d + 64] : buf[d - 64];
    float val = nv * c + rot * sn;
    int dd = swz ? (d ^ ((s & 7) << 3)) : d;
    size_t o = ((size_t)s * nheads + h) * HD + dd;
    ushort hh = f2bf(val);
    oh[o] = hh;
    ol[o] = f2bf(val - bf2f(hh));
}

// ---------------------------------------------------------------------------
// bf16x3 compensated MFMA GEMM, BM=BN=128, BK=32, 4 waves (each 64x64),
// double-buffered LDS (64 KB), STAGE(next)->COMPUTE(cur)->barrier pipeline.
// MODE 0: C = acc (+res)
// MODE 1: dual write: C = C2 = acc + res
// MODE 2: gate/up interleaved rows -> d = silu(g)*u -> Dh/Dl bf16 split
//         (wc=0 waves hold g, wc=1 hold u; exchange via LDS; D is [M][N/2])
// ---------------------------------------------------------------------------
template <int MODE>
__global__ __launch_bounds__(256, 2) void gemm_bf16x3(
    const ushort* __restrict__ Ah, const ushort* __restrict__ Al,
    const ushort* __restrict__ Bh, const ushort* __restrict__ Bl,
    const float* __restrict__ res, float* __restrict__ C,
    float* __restrict__ C2, ushort* __restrict__ Dh, ushort* __restrict__ Dl,
    int M, int N, int K) {
    __shared__ __align__(16) ushort sAh[2][128 * 32];
    __shared__ __align__(16) ushort sAl[2][128 * 32];
    __shared__ __align__(16) ushort sBh[2][128 * 32];
    __shared__ __align__(16) ushort sBl[2][128 * 32];

    // bijective XCD swizzle (grid size is a multiple of 8)
    unsigned nbx = gridDim.x;
    unsigned flat = blockIdx.y * nbx + blockIdx.x;
    unsigned cpx = (nbx * gridDim.y) >> 3;
    unsigned sflat = (flat & 7u) * cpx + (flat >> 3);
    int bx = (int)(sflat % nbx);
    int by = (int)(sflat / nbx);
    int bm = by * 128, bn = bx * 128;

    int tid = threadIdx.x;
    int lane = tid & 63, wave = tid >> 6;
    int wr = wave >> 1, wc = wave & 1;
    int r = lane & 15, kq = lane >> 4;

    int srow = tid >> 2;
    int sk = (tid & 3) * 8;
    const ushort* gAh = Ah + (size_t)(bm + srow) * K + sk;
    const ushort* gAl = Al + (size_t)(bm + srow) * K + sk;
    const ushort* gBh = Bh + (size_t)(bn + srow) * K + sk;
    const ushort* gBl = Bl + (size_t)(bn + srow) * K + sk;
    const size_t rstep = (size_t)64 * K;

    f32x4 acc[4][4] = {};

    auto STAGE = [&](int buf, int k0) {
        glds16(gAh + k0, &sAh[buf][tid * 8]);
        glds16(gAh + k0 + rstep, &sAh[buf][2048 + tid * 8]);
        glds16(gAl + k0, &sAl[buf][tid * 8]);
        glds16(gAl + k0 + rstep, &sAl[buf][2048 + tid * 8]);
        glds16(gBh + k0, &sBh[buf][tid * 8]);
        glds16(gBh + k0 + rstep, &sBh[buf][2048 + tid * 8]);
        glds16(gBl + k0, &sBl[buf][tid * 8]);
        glds16(gBl + k0 + rstep, &sBl[buf][2048 + tid * 8]);
    };
    auto COMPUTE = [&](int buf) {
        const ushort* pAh = &sAh[buf][(wr * 64 + r) * 32 + kq * 8];
        const ushort* pAl = &sAl[buf][(wr * 64 + r) * 32 + kq * 8];
        const ushort* pBh = &sBh[buf][(wc * 64 + r) * 32 + kq * 8];
        const ushort* pBl = &sBl[buf][(wc * 64 + r) * 32 + kq * 8];
        bf16x8 ah[4], al[4];
#pragma unroll
        for (int mi = 0; mi < 4; ++mi) {
            ah[mi] = *(const bf16x8*)(pAh + mi * 512);
            al[mi] = *(const bf16x8*)(pAl + mi * 512);
        }
#pragma unroll
        for (int ni = 0; ni < 4; ++ni) {
            bf16x8 bh = *(const bf16x8*)(pBh + ni * 512);
            bf16x8 bl = *(const bf16x8*)(pBl + ni * 512);
#pragma unroll
            for (int mi = 0; mi < 4; ++mi) {
                acc[mi][ni] = __builtin_amdgcn_mfma_f32_16x16x32_bf16(ah[mi], bh, acc[mi][ni], 0, 0, 0);
                acc[mi][ni] = __builtin_amdgcn_mfma_f32_16x16x32_bf16(al[mi], bh, acc[mi][ni], 0, 0, 0);
                acc[mi][ni] = __builtin_amdgcn_mfma_f32_16x16x32_bf16(ah[mi], bl, acc[mi][ni], 0, 0, 0);
            }
        }
    };

    STAGE(0, 0);
    __syncthreads();
    int cur = 0;
    for (int k0 = 32; k0 < K; k0 += 32) {
        STAGE(cur ^ 1, k0);
        COMPUTE(cur);
        __syncthreads();
        cur ^= 1;
    }
    COMPUTE(cur);

    if (MODE == 2) {
        // cross-wave g/u exchange; D[M][N/2]
        __syncthreads();
        float* X = (wr == 0) ? (float*)sAh : (float*)sBh;   // 64x64 fp32 = 16KB
        if (wc == 1) {
#pragma unroll
            for (int mi = 0; mi < 4; ++mi)
#pragma unroll
                for (int ni = 0; ni < 4; ++ni)
#pragma unroll
                    for (int j = 0; j < 4; ++j)
                        X[(mi * 16 + kq * 4 + j) * 64 + ni * 16 + r] = acc[mi][ni][j];
        }
        __syncthreads();
        if (wc == 0) {
            int ND = N >> 1;
#pragma unroll
            for (int mi = 0; mi < 4; ++mi)
#pragma unroll
                for (int ni = 0; ni < 4; ++ni)
#pragma unroll
                    for (int j = 0; j < 4; ++j) {
                        float g = acc[mi][ni][j];
                        float u = X[(mi * 16 + kq * 4 + j) * 64 + ni * 16 + r];
                        float dv = g / (1.0f + expf(-g)) * u;
                        int row = bm + wr * 64 + kq * 4 + mi * 16 + j;
                        int col = (bn >> 1) + ni * 16 + r;
                        size_t idx = (size_t)row * ND + col;
                        ushort hh = f2bf(dv);
                        Dh[idx] = hh;
                        Dl[idx] = f2bf(dv - bf2f(hh));
                    }
        }
        return;
    }

    int c0 = bn + wc * 64 + r;
    int r0 = bm + wr * 64 + kq * 4;
#pragma unroll
    for (int mi = 0; mi < 4; ++mi)
#pragma unroll
        for (int ni = 0; ni < 4; ++ni)
#pragma unroll
            for (int j = 0; j < 4; ++j) {
                int row = r0 + mi * 16 + j;
                int col = c0 + ni * 16;
                size_t idx = (size_t)row * N + col;
                float val = acc[mi][ni][j];
                if (res) val += res[idx];
                C[idx] = val;
                if (MODE == 1) C2[idx] = val;
            }
}

// ---------------------------------------------------------------------------
// MFMA flash attention, bf16x3, ATQ=128 (2 row-frags/wave), KV tile 64,
// double-buffered K/V staging (128 KB LDS, 1 block/CU). Each block processes
// q-tile bx then 15-bx (causal load balance). P overlays sKh/sKl[cur].
// ---------------------------------------------------------------------------
#define ATK 64

__global__ __launch_bounds__(256, 1) void attn_mfma_k(
    const ushort* __restrict__ Qhg, const ushort* __restrict__ Qlg,
    const ushort* __restrict__ Khg, const ushort* __restrict__ Klg,
    const ushort* __restrict__ Vhg, const ushort* __restrict__ Vlg,
    const int* __restrict__ keys_idxs, const int* __restrict__ hs_idxs,
    ushort* __restrict__ Chg, ushort* __restrict__ Clg) {
    __shared__ __align__(16) ushort sKh[2][64 * 128];
    __shared__ __align__(16) ushort sKl[2][64 * 128];
    __shared__ __align__(16) ushort sVh[2][128 * 64];
    __shared__ __align__(16) ushort sVl[2][128 * 64];
    __shared__ int kidx[2][ATK];
    __shared__ int qpos[128];

    int h = blockIdx.y;
    int kvh = h >> 1;
    int tid = threadIdx.x;
    int lane = tid & 63, wv = tid >> 6;
    int r = lane & 15, kq = lane >> 4;
    int xorv = (lane & 7) << 3;
    const float scale = 0.088388347648318447f;
    const size_t kvstride = (size_t)NKVH * HD;   // 1024

    const ushort* gKh = Khg + ((size_t)(tid >> 4) * NKVH + kvh) * HD + (tid & 15) * 8;
    const ushort* gKl = Klg + ((size_t)(tid >> 4) * NKVH + kvh) * HD + (tid & 15) * 8;
    const ushort* gVh = Vhg + ((size_t)kvh * HD + (tid >> 3)) * S_LEN + (tid & 7) * 8;
    const ushort* gVl = Vlg + ((size_t)kvh * HD + (tid >> 3)) * S_LEN + (tid & 7) * 8;

    for (int sub = 0; sub < 2; ++sub) {
        int qt = (sub == 0) ? blockIdx.x : (15 - blockIdx.x);
        int q0 = qt * 128;
        if (tid < 128) qpos[tid] = hs_idxs[q0 + tid];

        // Q fragments: 2 row-frags x 4 k-steps (hi & lo)
        bf16x8 qh[2][4], ql[2][4];
#pragma unroll
        for (int fr = 0; fr < 2; ++fr) {
            int qrow = q0 + wv * 32 + fr * 16 + r;
            const ushort* qb = Qhg + ((size_t)qrow * NHEADS + h) * HD + kq * 8;
            const ushort* qb2 = Qlg + ((size_t)qrow * NHEADS + h) * HD + kq * 8;
#pragma unroll
            for (int ks = 0; ks < 4; ++ks) {
                qh[fr][ks] = *(const bf16x8*)(qb + ks * 32);
                ql[fr][ks] = *(const bf16x8*)(qb2 + ks * 32);
            }
        }

        // stage tile 0 into buf 0
#pragma unroll
        for (int p = 0; p < 4; ++p) {
            glds16(gKh + (size_t)p * 16 * kvstride, &sKh[0][(tid + p * 256) * 8]);
            glds16(gKl + (size_t)p * 16 * kvstride, &sKl[0][(tid + p * 256) * 8]);
            glds16(gVh + (size_t)p * 32 * S_LEN, &sVh[0][(tid + p * 256) * 8]);
            glds16(gVl + (size_t)p * 32 * S_LEN, &sVl[0][(tid + p * 256) * 8]);
        }
        if (tid < ATK) kidx[0][tid] = keys_idxs[tid];
        __syncthreads();   // tile0 resident (vmcnt drained), qpos visible

        int hs_max = qpos[127];
        int qp[2][4];
#pragma unroll
        for (int fr = 0; fr < 2; ++fr)
#pragma unroll
            for (int j = 0; j < 4; ++j) qp[fr][j] = qpos[wv * 32 + fr * 16 + kq * 4 + j];

        f32x4 o[2][8] = {};
        float m_run[2][4] = {{-3.0e38f, -3.0e38f, -3.0e38f, -3.0e38f},
                             {-3.0e38f, -3.0e38f, -3.0e38f, -3.0e38f}};
        float l_run[2][4] = {};
        int cur = 0;

        for (int kt = 0;; ++kt) {
            int k0 = kt * ATK;
            if (k0 >= S_LEN || keys_idxs[k0] > hs_max) break;
            // prefetch next tile into cur^1 (clamped)
            int kn = (k0 + ATK < S_LEN) ? (k0 + ATK) : k0;
            {
                int nb = cur ^ 1;
                const size_t koff = (size_t)kn * kvstride;
#pragma unroll
                for (int p = 0; p < 4; ++p) {
                    glds16(gKh + koff + (size_t)p * 16 * kvstride, &sKh[nb][(tid + p * 256) * 8]);
                    glds16(gKl + koff + (size_t)p * 16 * kvstride, &sKl[nb][(tid + p * 256) * 8]);
                    glds16(gVh + kn + (size_t)p * 32 * S_LEN, &sVh[nb][(tid + p * 256) * 8]);
                    glds16(gVl + kn + (size_t)p * 32 * S_LEN, &sVl[nb][(tid + p * 256) * 8]);
                }
                if (tid < ATK) kidx[nb][tid] = keys_idxs[kn + tid];
            }

            // ---- S = Q K^T (3-term), 2 row-frags ----
            f32x4 sf[2][4] = {};
#pragma unroll
            for (int ks = 0; ks < 4; ++ks) {
                int kb = (ks * 32 + kq * 8) ^ xorv;
#pragma unroll
                for (int f = 0; f < 4; ++f) {
                    bf16x8 kh = *(const bf16x8*)(&sKh[cur][(f * 16 + r) * 128 + kb]);
                    bf16x8 kl = *(const bf16x8*)(&sKl[cur][(f * 16 + r) * 128 + kb]);
#pragma unroll
                    for (int fr = 0; fr < 2; ++fr) {
                        sf[fr][f] = __builtin_amdgcn_mfma_f32_16x16x32_bf16(qh[fr][ks], kh, sf[fr][f], 0, 0, 0);
                        sf[fr][f] = __builtin_amdgcn_mfma_f32_16x16x32_bf16(ql[fr][ks], kh, sf[fr][f], 0, 0, 0);
                        sf[fr][f] = __builtin_amdgcn_mfma_f32_16x16x32_bf16(qh[fr][ks], kl, sf[fr][f], 0, 0, 0);
                    }
                }
            }

            // ---- online softmax ----
            int kj[4];
#pragma unroll
            for (int f = 0; f < 4; ++f) kj[f] = kidx[cur][f * 16 + r];
            float alj[2][4];
#pragma unroll
            for (int fr = 0; fr < 2; ++fr)
#pragma unroll
                for (int j = 0; j < 4; ++j) {
#pragma unroll
                    for (int f = 0; f < 4; ++f)
                        sf[fr][f][j] = sf[fr][f][j] * scale + ((kj[f] <= qp[fr][j]) ? 0.0f : -1.0e9f);
                    float m0 = fmaxf(fmaxf(sf[fr][0][j], sf[fr][1][j]), fmaxf(sf[fr][2][j], sf[fr][3][j]));
#pragma unroll
                    for (int off = 1; off < 16; off <<= 1) m0 = fmaxf(m0, __shfl_xor(m0, off));
                    float mn = fmaxf(m_run[fr][j], m0);
                    alj[fr][j] = __expf(m_run[fr][j] - mn);
                    m_run[fr][j] = mn;
                    float rsum = 0.0f;
#pragma unroll
                    for (int f = 0; f < 4; ++f) {
                        sf[fr][f][j] = __expf(sf[fr][f][j] - mn);
                        rsum += sf[fr][f][j];
                    }
#pragma unroll
                    for (int off = 1; off < 16; off <<= 1) rsum += __shfl_xor(rsum, off);
                    l_run[fr][j] = l_run[fr][j] * alj[fr][j] + rsum;
                }
#pragma unroll
            for (int fr = 0; fr < 2; ++fr)
#pragma unroll
                for (int df = 0; df < 8; ++df)
#pragma unroll
                    for (int j = 0; j < 4; ++j) o[fr][df][j] *= alj[fr][j];

            __syncthreads();   // all QK reads of K[cur] done -> safe to overlay P

            // ---- P split hi/lo -> overlay on sKh/sKl[cur], rows [128][64] ----
#pragma unroll
            for (int fr = 0; fr < 2; ++fr)
#pragma unroll
                for (int j = 0; j < 4; ++j) {
                    int qloc = wv * 32 + fr * 16 + kq * 4 + j;
                    int swz = (qloc & 7) << 3;
                    int rowb = qloc * 64;
#pragma unroll
                    for (int f = 0; f < 4; ++f) {
                        float pv = sf[fr][f][j];
                        unsigned u = __float_as_uint(pv);
                        float hi = __uint_as_float(u & 0xFFFF0000u);
                        int a = rowb + ((f * 16 + r) ^ swz);
                        sKh[cur][a] = (ushort)(u >> 16);
                        sKl[cur][a] = (ushort)(__float_as_uint(pv - hi) >> 16);
                    }
                }

            // ---- O += P V (3-term); own-wave P rows, no barrier needed ----
#pragma unroll
            for (int kv0 = 0; kv0 < 2; ++kv0) {
                int kb = (kv0 * 32 + kq * 8) ^ xorv;
                bf16x8 pah[2], pal[2];
#pragma unroll
                for (int fr = 0; fr < 2; ++fr) {
                    int prow = wv * 32 + fr * 16 + r;
                    pah[fr] = *(const bf16x8*)(&sKh[cur][prow * 64 + kb]);
                    pal[fr] = *(const bf16x8*)(&sKl[cur][prow * 64 + kb]);
                }
#pragma unroll
                for (int df = 0; df < 8; ++df) {
                    bf16x8 vh = *(const bf16x8*)(&sVh[cur][(df * 16 + r) * 64 + kb]);
                    bf16x8 vl = *(const bf16x8*)(&sVl[cur][(df * 16 + r) * 64 + kb]);
#pragma unroll
                    for (int fr = 0; fr < 2; ++fr) {
                        o[fr][df] = __builtin_amdgcn_mfma_f32_16x16x32_bf16(pah[fr], vh, o[fr][df], 0, 0, 0);
                        o[fr][df] = __builtin_amdgcn_mfma_f32_16x16x32_bf16(pal[fr], vh, o[fr][df], 0, 0, 0);
                        o[fr][df] = __builtin_amdgcn_mfma_f32_16x16x32_bf16(pah[fr], vl, o[fr][df], 0, 0, 0);
                    }
                }
            }
            __syncthreads();   // PV reads of V[cur]/P done; next-tile loads drained
            cur ^= 1;
        }

        // epilogue: normalize + bf16 split store
#pragma unroll
        for (int fr = 0; fr < 2; ++fr)
#pragma unroll
            for (int j = 0; j < 4; ++j) {
                float invl = 1.0f / l_run[fr][j];
                int qg = q0 + wv * 32 + fr * 16 + kq * 4 + j;
#pragma unroll
                for (int df = 0; df < 8; ++df) {
                    int d = df * 16 + r;
                    float val = o[fr][df][j] * invl;
                    size_t idx = ((size_t)qg * NHEADS + h) * HD + d;
                    ushort hh = f2bf(val);
                    Chg[idx] = hh;
                    Clg[idx] = f2bf(val - bf2f(hh));
                }
            }
        __syncthreads();   // LDS reuse safety before next sub-problem
    }
}

// ---------------------------------------------------------------------------
// Importance: softmax (no mask) of last q row vs all keys, per head.
// Reads bf16 hi/lo Q (linear) and K (d XOR-swizzled by s&7).
// ---------------------------------------------------------------------------
__global__ __launch_bounds__(256) void importance_scores_k(
    const ushort* __restrict__ Qh, const ushort* __restrict__ Ql,
    const ushort* __restrict__ Kh, const ushort* __restrict__ Kl,
    float* __restrict__ imp_ws) {
    int h = blockIdx.x;
    int kv = h >> 1;
    int tid = threadIdx.x;
    __shared__ float qrow[HD];
    __shared__ float sc[S_LEN];
    __shared__ float red[256];
    if (tid < HD) {
        size_t qi = ((size_t)(S_LEN - 1) * NHEADS + h) * HD + tid;
        qrow[tid] = bf2f(Qh[qi]) + bf2f(Ql[qi]);
    }
    __syncthreads();
    const float scale = 0.088388347648318447f;
    float lmax = -3.0e38f;
#pragma unroll
    for (int rep = 0; rep < 8; ++rep) {
        int j = tid + rep * 256;
        size_t base = ((size_t)j * NKVH + kv) * HD;
        int swz = (j & 7) << 3;
        float dot = 0.0f;
        for (int d = 0; d < HD; ++d) {
            int dd = d ^ swz;
            dot += qrow[d] * (bf2f(Kh[base + dd]) + bf2f(Kl[base + dd]));
        }
        float sval = dot * scale;
        sc[j] = sval;
        lmax = fmaxf(lmax, sval);
    }
    red[tid] = lmax;
    __syncthreads();
    for (int off = 128; off > 0; off >>= 1) {
        if (tid < off) red[tid] = fmaxf(red[tid], red[tid + off]);
        __syncthreads();
    }
    float m = red[0];
    __syncthreads();
    float lsum = 0.0f;
    float evals[8];
#pragma unroll
    for (int rep = 0; rep < 8; ++rep) {
        int j = tid + rep * 256;
        float e = expf(sc[j] - m);
        evals[rep] = e;
        lsum += e;
    }
    red[tid] = lsum;
    __syncthreads();
    for (int off = 128; off > 0; off >>= 1) {
        if (tid < off) red[tid] += red[tid + off];
        __syncthreads();
    }
    float inv = 1.0f / red[0];
#pragma unroll
    for (int rep = 0; rep < 8; ++rep) {
        int j = tid + rep * 256;
        imp_ws[(size_t)h * S_LEN + j] = evals[rep] * inv;
    }
}

__global__ __launch_bounds__(256) void importance_combine_k(const float* __restrict__ imp_ws,
                                                            float* __restrict__ out) {
    int j = blockIdx.x * 256 + threadIdx.x;
    float sum = 0.0f;
    for (int h = 0; h < NHEADS; ++h) sum += imp_ws[(size_t)h * S_LEN + j];
    out[j] = (j == S_LEN - 1) ? 3.0e38f : sum * (1.0f / NHEADS);
}

// ---------------------------------------------------------------------------
extern "C" void kernel_launch(void* const* d_in, const int* in_sizes, int n_in,
                              void* d_out, int out_size, void* d_ws, size_t ws_size,
                              hipStream_t stream) {
    const float* hidden    = (const float*)d_in[0];
    const int*   keys_idxs = (const int*)d_in[2];
    const int*   hs_idxs   = (const int*)d_in[3];
    const int*   positions = (const int*)d_in[4];
    const float* ln_in_w   = (const float*)d_in[5];
    const float* q_w       = (const float*)d_in[6];
    const float* k_w       = (const float*)d_in[7];
    const float* v_w       = (const float*)d_in[8];
    const float* q_norm_w  = (const float*)d_in[9];
    const float* k_norm_w  = (const float*)d_in[10];
    const float* o_w       = (const float*)d_in[11];
    const float* ln_post_w = (const float*)d_in[12];
    const float* gate_w    = (const float*)d_in[13];
    const float* up_w      = (const float*)d_in[14];
    const float* down_w    = (const float*)d_in[15];

    float* out = (float*)d_out;
    float* ws = (float*)d_ws;
    const size_t MF = 1024ull * 1024;

    // Region plan (floats; peak 20 MF = 80 MB):
    //  [0,4M)    Xh/Xl -> Qbh/Qbl -> Yh/Yl (bf16)
    //  [4M,12M)  Wqkv h/l -> {Kb [4,6M), Vt [6,8M), imp [8M,..), Ch/Cl [8,12M)}
    //            -> Wgu h/l
    //  [12M,20M) qkv fp32 -> {hb [12,16M), Wo [16,20M)} -> {D [12,16M), Wd [16,20M)}
    ushort* Xh  = (ushort*)(ws);
    ushort* Xl  = (ushort*)(ws + 2 * MF);
    ushort* Wh  = (ushort*)(ws + 4 * MF);
    ushort* Wl  = (ushort*)(ws + 8 * MF);
    float*  qkv = ws + 12 * MF;
    ushort* Qbh = (ushort*)(ws);
    ushort* Qbl = (ushort*)(ws + 2 * MF);
    ushort* Kbh = (ushort*)(ws + 4 * MF);
    ushort* Kbl = (ushort*)(ws + 5 * MF);
    ushort* Vth = (ushort*)(ws + 6 * MF);
    ushort* Vtl = (ushort*)(ws + 7 * MF);
    float*  imp = ws + 8 * MF;
    ushort* Ch  = (ushort*)(ws + 8 * MF);
    ushort* Cl  = (ushort*)(ws + 10 * MF);
    float*  hb  = ws + 12 * MF;
    ushort* Woh = (ushort*)(ws + 16 * MF);
    ushort* Wol = (ushort*)(ws + 18 * MF);
    ushort* Yh  = (ushort*)(ws);
    ushort* Yl  = (ushort*)(ws + 2 * MF);
    ushort* Dh  = (ushort*)(ws + 12 * MF);
    ushort* Dl  = (ushort*)(ws + 14 * MF);
    ushort* Wdh = (ushort*)(ws + 16 * MF);
    ushort* Wdl = (ushort*)(ws + 18 * MF);

    // 1. x = rms(hidden) -> bf16 split
    rmsnorm_split_k<<<S_LEN, 256, 0, stream>>>(hidden, ln_in_w, Xh, Xl);

    // 2. fused QKV projection
    transpose_split_qkv_k<<<dim3(32, 32, 3), 256, 0, stream>>>(q_w, k_w, v_w, Wh, Wl);
    gemm_bf16x3<0><<<dim3(32, 16), 256, 0, stream>>>(
        Xh, Xl, Wh, Wl, nullptr, qkv, nullptr, nullptr, nullptr, S_LEN, 4096, HDIM);

    // 3. per-head norm + rope -> bf16 split attention layouts (q linear, k swizzled)
    qk_rope_split_k<<<dim3(S_LEN, NHEADS), 128, 0, stream>>>(
        qkv, q_norm_w, positions, Qbh, Qbl, NHEADS, 0, 0);
    qk_rope_split_k<<<dim3(S_LEN, NKVH), 128, 0, stream>>>(
        qkv, k_norm_w, positions, Kbh, Kbl, NKVH, 2048, 1);

    // 4. V transpose conversion
    conv_vt_k<<<dim3(S_LEN / 64, HD / 64, NKVH), 256, 0, stream>>>(qkv, Vth, Vtl);

    // 5. importance (reads bf16 Q/K; scratch at [8M,..) before Ch reuses it)
    importance_scores_k<<<NHEADS, 256, 0, stream>>>(Qbh, Qbl, Kbh, Kbl, imp);
    importance_combine_k<<<S_LEN / 256, 256, 0, stream>>>(imp, out + (size_t)S_LEN * HDIM);

    // 6. MFMA flash attention -> Ch/Cl
    attn_mfma_k<<<dim3(16, 16), 256, 0, stream>>>(
        Qbh, Qbl, Kbh, Kbl, Vth, Vtl, keys_idxs, hs_idxs, Ch, Cl);

    // 7. h = hidden + ctx @ o_w  (dual write: hb and out)
    transpose_split_k<<<dim3(32, 32), 256, 0, stream>>>(o_w, Woh, Wol, HDIM, HDIM, 0, 0);
    gemm_bf16x3<1><<<dim3(16, 16), 256, 0, stream>>>(
        Ch, Cl, Woh, Wol, hidden, hb, out, nullptr, nullptr, S_LEN, HDIM, HDIM);

    // 8. y = rms(h) -> bf16 split
    rmsnorm_split_k<<<S_LEN, 256, 0, stream>>>(hb, ln_post_w, Yh, Yl);

    // 9. MLP in three FF-chunks of 2048; gate/up interleaved + silu fused in GEMM
    for (int c = 0; c < 3; ++c) {
        transpose_split_gu_k<<<dim3(32, 32, 2), 256, 0, stream>>>(gate_w, up_w, Wh, Wl, c * 2048);
        gemm_bf16x3<2><<<dim3(32, 16), 256, 0, stream>>>(
            Yh, Yl, Wh, Wl, nullptr, nullptr, nullptr, Dh, Dl, S_LEN, 4096, HDIM);
        transpose_split_k<<<dim3(32, 32), 256, 0, stream>>>(
            down_w + (size_t)c * 2048 * HDIM, Wdh, Wdl, 2048, HDIM, 0, 0);
        gemm_bf16x3<0><<<dim3(16, 16), 256, 0, stream>>>(
            Dh, Dl, Wdh, Wdl, out, out, nullptr, nullptr, nullptr, S_LEN, HDIM, 2048);
    }
}